// Round 4
// baseline (91.950 us; speedup 1.0000x reference)
//
#include <hip/hip_runtime.h>

// Problem: A=1, B=32, M=32, H=1024, E=8, N=1024 (all fp32)
// out[b,e] = mask[b,e] * sum_h (sum_m hidden[b,m,h]) * (sum_n weight[e,h,n])
//
// Single fused kernel, 512 blocks = 2/CU exactly.
// Block i: e = i>>6, h-tile [h0, h0+16) with h0 = (i&63)*16.
//   step 1: hs[b][hh] = sum_m hidden[b,m,h0+hh]   (64 KB, L2-hot, 8x shared)
//   step 2: wsum[hh]  = sum_n weight[e,h0+hh,n]   (mandatory 32 MB, read once)
//   step 3: per-b dot over the 16-h tile -> one fp32 atomicAdd per (b,e).
// out zero-initialized by a 1 KB memset node.

#define Bdim 32
#define Mdim 32
#define Hdim 1024
#define Edim 8
#define Ndim 1024

__global__ __launch_bounds__(256) void fused_kernel(
    const float* __restrict__ hidden,    // (B,M,H)
    const float* __restrict__ weight,    // (E,H,N)
    const float* __restrict__ sparsity,  // (B,E) flat
    float* __restrict__ out)             // (B,E) flat, pre-zeroed
{
    __shared__ float4 hsA[Bdim][4];   // m in [0,16) partial, per (b, h-quad)
    __shared__ float4 hsB[Bdim][4];   // m in [16,32) partial
    __shared__ float  wsum_s[16];

    const int tid = threadIdx.x;
    const int e   = blockIdx.x >> 6;          // 0..7
    const int h0  = (blockIdx.x & 63) * 16;   // h tile base

    // ---- step 1: hidden M-reduction for this h-tile, all b ----
    {
        const int b    = tid >> 3;        // 0..31
        const int half = (tid >> 2) & 1;  // m half
        const int q    = tid & 3;         // which float4 of the 16-float tile
        const float4* base = reinterpret_cast<const float4*>(hidden)
                             + b * (Mdim * Hdim / 4) + (h0 >> 2) + q
                             + half * 16 * (Hdim / 4);
        float4 acc = {0.f, 0.f, 0.f, 0.f};
        #pragma unroll
        for (int k = 0; k < 16; ++k) {
            float4 v = base[k * (Hdim / 4)];
            acc.x += v.x; acc.y += v.y; acc.z += v.z; acc.w += v.w;
        }
        if (half == 0) hsA[b][q] = acc; else hsB[b][q] = acc;
    }

    // ---- step 2: weight N-reduction, 16 rows (e, h0..h0+16) ----
    const int wv   = tid >> 6;   // wave 0..3
    const int lane = tid & 63;
    const float4* w4 = reinterpret_cast<const float4*>(weight);
    #pragma unroll
    for (int j = 0; j < 4; ++j) {
        const int hh  = wv * 4 + j;
        const int row = e * Hdim + h0 + hh;   // 0..8191
        float s = 0.f;
        #pragma unroll
        for (int c = 0; c < 4; ++c) {
            float4 v = w4[row * (Ndim / 4) + c * 64 + lane];
            s += (v.x + v.y) + (v.z + v.w);
        }
        #pragma unroll
        for (int off = 32; off > 0; off >>= 1)
            s += __shfl_xor(s, off, 64);
        if (lane == 0) wsum_s[hh] = s;
    }
    __syncthreads();

    // ---- step 3: per-b dot over the tile, one atomic per (b,e) ----
    if (tid < Bdim) {
        const int b = tid;
        float p = 0.f;
        #pragma unroll
        for (int q = 0; q < 4; ++q) {
            float4 hA = hsA[b][q];
            float4 hB = hsB[b][q];
            p += (hA.x + hB.x) * wsum_s[q * 4 + 0]
               + (hA.y + hB.y) * wsum_s[q * 4 + 1]
               + (hA.z + hB.z) * wsum_s[q * 4 + 2]
               + (hA.w + hB.w) * wsum_s[q * 4 + 3];
        }
        atomicAdd(&out[b * Edim + e], p * sparsity[b * Edim + e]);
    }
}

extern "C" void kernel_launch(void* const* d_in, const int* in_sizes, int n_in,
                              void* d_out, int out_size, void* d_ws, size_t ws_size,
                              hipStream_t stream) {
    const float* hidden   = (const float*)d_in[0];  // (1,32,32,1024)
    const float* sparsity = (const float*)d_in[1];  // (1,32,1,8)
    const float* weight   = (const float*)d_in[2];  // (1,8,1024,1024)
    float* out = (float*)d_out;                     // (1,32,8) = 256 floats

    hipMemsetAsync(out, 0, out_size * sizeof(float), stream);
    fused_kernel<<<512, 256, 0, stream>>>(hidden, weight, sparsity, out);
}

// Round 5
// 82.045 us; speedup vs baseline: 1.1207x; 1.1207x over previous
//
#include <hip/hip_runtime.h>

// Problem: A=1, B=32, M=32, H=1024, E=8, N=1024 (all fp32)
// out[b,e] = mask[b,e] * sum_h (sum_m hidden[b,m,h]) * (sum_n weight[e,h,n])
//
// ws layout (floats): [0, E*H)          wsum  (8192)
//                     [E*H, E*H + B*H)  hsum  (32768)
//
// Best-measured structure (R1/R2, ~79-80 us total; harness floor ~65 us):
// two kernels, no atomics, no extra memset nodes. Hidden blocks dispatched
// FIRST so their strided-load phase overlaps the weight stream instead of
// trailing it.

#define Bdim 32
#define Mdim 32
#define Hdim 1024
#define Edim 8
#define Ndim 1024

// Kernel A: blocks [0,32): hidden M-reduction — thread per (b, h/4), float4
//                          loads, fully coalesced across h.
//           blocks [32,544): weight rows — one wave per 4 rows of N=1024,
//                          float4 loads (16 B/lane), shuffle reduce.
__global__ __launch_bounds__(256) void reduce_kernel(
    const float* __restrict__ hidden,   // (B,M,H)
    const float* __restrict__ weight,   // (E,H,N)
    float* __restrict__ ws)
{
    if (blockIdx.x < 32) {
        // 32 blocks x 256 threads = 8192 threads = B*H/4
        const int idx = blockIdx.x * 256 + threadIdx.x;  // b*256 + h/4
        const int b = idx >> 8;
        const float4* p4 = reinterpret_cast<const float4*>(hidden)
                           + b * (Mdim * Hdim / 4) + (idx & 255);
        float4 acc = {0.f, 0.f, 0.f, 0.f};
        #pragma unroll
        for (int m = 0; m < Mdim; ++m) {
            float4 v = p4[m * (Hdim / 4)];
            acc.x += v.x; acc.y += v.y; acc.z += v.z; acc.w += v.w;
        }
        reinterpret_cast<float4*>(ws + Edim * Hdim)[idx] = acc;
    } else {
        const int wave = (blockIdx.x - 32) * 4 + (threadIdx.x >> 6);
        const int lane = threadIdx.x & 63;
        const float4* w4 = reinterpret_cast<const float4*>(weight);
        #pragma unroll
        for (int r = 0; r < 4; ++r) {
            const int row = wave * 4 + r;          // row = e*H + h, 0..8191
            float s = 0.f;
            #pragma unroll
            for (int j = 0; j < 4; ++j) {
                float4 v = w4[row * (Ndim / 4) + j * 64 + lane];
                s += (v.x + v.y) + (v.z + v.w);
            }
            #pragma unroll
            for (int off = 32; off > 0; off >>= 1)
                s += __shfl_xor(s, off, 64);
            if (lane == 0) ws[row] = s;
        }
    }
}

// Kernel B: 256 waves, one per (b,e); dot over h=1024 of hsum[b,:]*wsum[e,:]
// via float4 loads, masked by sparsity[b,e]. L2-hot (~160 KB).
__global__ __launch_bounds__(256) void dot_kernel(
    const float* __restrict__ ws,
    const float* __restrict__ sparsity,  // (B,E) flat
    float* __restrict__ out)             // (B,E) flat
{
    const int o = blockIdx.x * 4 + (threadIdx.x >> 6);   // b*E + e, 0..255
    const int lane = threadIdx.x & 63;
    const int b = o >> 3;
    const int e = o & 7;
    const float4* hsum4 = reinterpret_cast<const float4*>(ws + Edim * Hdim + b * Hdim);
    const float4* wsum4 = reinterpret_cast<const float4*>(ws + e * Hdim);
    float s = 0.f;
    #pragma unroll
    for (int j = 0; j < 4; ++j) {
        const int h4 = j * 64 + lane;
        float4 a = hsum4[h4];
        float4 w = wsum4[h4];
        s += a.x * w.x + a.y * w.y + a.z * w.z + a.w * w.w;
    }
    #pragma unroll
    for (int off = 32; off > 0; off >>= 1)
        s += __shfl_xor(s, off, 64);
    if (lane == 0) out[o] = s * sparsity[o];
}

extern "C" void kernel_launch(void* const* d_in, const int* in_sizes, int n_in,
                              void* d_out, int out_size, void* d_ws, size_t ws_size,
                              hipStream_t stream) {
    const float* hidden   = (const float*)d_in[0];  // (1,32,32,1024)
    const float* sparsity = (const float*)d_in[1];  // (1,32,1,8)
    const float* weight   = (const float*)d_in[2];  // (1,8,1024,1024)
    float* out = (float*)d_out;                     // (1,32,8)
    float* ws  = (float*)d_ws;

    reduce_kernel<<<544, 256, 0, stream>>>(hidden, weight, ws);
    dot_kernel<<<64, 256, 0, stream>>>(ws, sparsity, out);
}